// Round 1
// baseline (297.112 us; speedup 1.0000x reference)
//
#include <hip/hip_runtime.h>
#include <hip/hip_bf16.h>

// Problem constants (from reference)
#define BB    16
#define LQ    64
#define LD    2048
#define HH    1024
#define DIM   128
#define MAXK  513          // LD/PF + 1 with PF=4
#define SCH   9            // ceil(513/64) cluster chunks for simmax
#define DGRID 1024         // d-encode blocks (32768 / 32)
#define QGRID 32           // q-encode blocks (1024 / 32)

typedef __attribute__((ext_vector_type(8))) short short8;
typedef __attribute__((ext_vector_type(4))) float f32x4;

__device__ __forceinline__ float b2f(ushort u) {
    union { float f; unsigned int u32; } c; c.u32 = ((unsigned int)u) << 16; return c.f;
}
__device__ __forceinline__ ushort f2b_rn(float f) {
    unsigned int x = __float_as_uint(f);
    return (ushort)((x + 0x7fffu + ((x >> 16) & 1u)) >> 16);
}

// async global->LDS, 16B/lane; LDS dest = wave-uniform base + lane*16
__device__ __forceinline__ void gld16(void* lds, const void* g) {
    __builtin_amdgcn_global_load_lds(
        (const __attribute__((address_space(1))) unsigned int*)g,
        (__attribute__((address_space(3))) unsigned int*)lds,
        16, 0, 0);
}

// ---------------------------------------------------------------------------
// Fused prep: blocks 0..511 transpose+round W -> Wt bf16; 512..527 kvals.
__global__ __launch_bounds__(256) void prep_kb_kernel(
    const float* __restrict__ W,
    const int*   __restrict__ d_mask,
    const int*   __restrict__ pf,
    ushort*      __restrict__ Wt,
    int*         __restrict__ kvals)
{
    __shared__ int red[4];
    int bid = blockIdx.x, t = threadIdx.x;
    if (bid < 512) {
        int idx = bid * 256 + t;     // < H*DIM = 131072
        int h = idx >> 7;            // row in H
        int n = idx & 127;           // col in DIM
        Wt[n * HH + h] = f2b_rn(W[idx]);
    } else {
        int b = bid - 512;
        int lane = t & 63, wave = t >> 6;
        int s = 0;
        for (int i = t; i < LD; i += 256) s += (d_mask[b * LD + i] > 0) ? 1 : 0;
        #pragma unroll
        for (int m = 1; m < 64; m <<= 1) s += __shfl_xor(s, m);
        if (lane == 0) red[wave] = s;
        __syncthreads();
        if (t == 0) {
            int v = red[0] + red[1] + red[2] + red[3];
            if (v < 2) v = 2;
            int pfv = pf[0];
            if (pfv < 1 || pfv > LD) pfv = 4;   // defensive
            kvals[b] = v / pfv + 1;
        }
    }
}

// ---------------------------------------------------------------------------
// Encode: 32-row x 128-col tile, 256 threads = 4 waves: wave w -> rows
// (w&1)*16, ct-group (w>>1)*4. BK=32, double-buffered LDS filled only via
// gld16, one barrier/chunk. 2 MFMA passes: A split hi+lo (exact), W rounded
// bf16. Epilogue: bias, cross-wave row norm, mask, coalesced store (NO
// atomics -- pooling moved to pool_kernel; the 4.2M memory-side atomicAdds
// were ~half the kernel time, WRITE_SIZE matched 4B/atomic exactly).
__global__ __launch_bounds__(256, 4) void encode_kernel(
    const float*  __restrict__ Xd,      // [32768][H]
    const float*  __restrict__ Xq,      // [1024][H]
    const ushort* __restrict__ Wt,      // [DIM][H] bf16 rounded
    const float*  __restrict__ bias,    // [DIM]
    const int*    __restrict__ mask_d,  // [32768]
    const int*    __restrict__ mask_q,  // [1024]
    float*        __restrict__ d_repr,  // [32768][DIM]
    float*        __restrict__ q_repr)  // [1024][DIM]
{
    __shared__ __align__(16) uint4 buf[2][768];   // 24 KB
    __shared__ float ssh[32][2];

    const int bid = blockIdx.x;
    const bool isq = bid >= DGRID;
    const float* X = isq ? Xq : Xd;
    const long row0 = isq ? (long)(bid - DGRID) * 32 : (long)bid * 32;

    const int t = threadIdx.x;
    const int w = t >> 6, lane = t & 63;
    const int m16 = lane & 15, quad = lane >> 4;
    const int rh = w & 1, ch = w >> 1;

    // staging sources (per lane), advance 32 elements per chunk
    const float*  gA  = X + (row0 + w * 8 + (lane >> 3)) * HH
                          + (((lane & 7) ^ ((lane >> 3) & 7)) * 4);
    const ushort* gB0 = Wt + (long)(w * 32 + (lane >> 2)) * HH
                           + (((lane & 3) ^ ((lane >> 4) & 3)) * 8);
    const ushort* gB1 = gB0 + 16 * HH;

    f32x4 acc[4];
    #pragma unroll
    for (int j = 0; j < 4; ++j) acc[j] = (f32x4){0.f, 0.f, 0.f, 0.f};

    // prologue: stage chunk 0
    gld16(&buf[0][w * 64], gA);
    gld16(&buf[0][256 + w * 128], gB0);
    gld16(&buf[0][256 + w * 128 + 64], gB1);

    const int sw = m16 & 7;
    const int bsw = m16 >> 2;
    const int au = (rh * 16 + m16) * 8;

    for (int c = 0; c < 32; ++c) {
        __syncthreads();                 // drains vmcnt: buf[c&1] staged
        const int cur = c & 1;

        if (c < 31) {                    // prefetch c+1 into other buffer
            const int nxt = cur ^ 1;
            const int ko = (c + 1) * 32;
            gld16(&buf[nxt][w * 64], gA + ko);
            gld16(&buf[nxt][256 + w * 128], gB0 + ko);
            gld16(&buf[nxt][256 + w * 128 + 64], gB1 + ko);
        }

        float4 va0 = *(const float4*)&buf[cur][au + ((2 * quad) ^ sw)];
        float4 va1 = *(const float4*)&buf[cur][au + ((2 * quad + 1) ^ sw)];
        float av[8];
        *(float4*)(av) = va0; *(float4*)(av + 4) = va1;
        short8 ah, al;
        #pragma unroll
        for (int j = 0; j < 8; ++j) {
            unsigned int ux = __float_as_uint(av[j]);
            ah[j] = (short)(ux >> 16);
            float hif = __uint_as_float(ux & 0xffff0000u);
            al[j] = (short)(__float_as_uint(av[j] - hif) >> 16);
        }

        #pragma unroll
        for (int cti = 0; cti < 4; ++cti) {
            const int ct = ch * 4 + cti;
            short8 bf = *(const short8*)&buf[cur][256 + (ct * 16 + m16) * 4 + (quad ^ bsw)];
            acc[cti] = __builtin_amdgcn_mfma_f32_16x16x32_bf16(ah, bf, acc[cti], 0, 0, 0);
            acc[cti] = __builtin_amdgcn_mfma_f32_16x16x32_bf16(al, bf, acc[cti], 0, 0, 0);
        }
    }

    // epilogue: bias, cross-wave row norm (cols split across ch), mask, store
    float bia[4];
    #pragma unroll
    for (int cti = 0; cti < 4; ++cti) bia[cti] = bias[(ch * 4 + cti) * 16 + m16];

    float vv[4][4];
    float ssp[4] = {0.f, 0.f, 0.f, 0.f};
    #pragma unroll
    for (int cti = 0; cti < 4; ++cti)
        #pragma unroll
        for (int r = 0; r < 4; ++r) {
            vv[cti][r] = acc[cti][r] + bia[cti];
            ssp[r] += vv[cti][r] * vv[cti][r];
        }
    #pragma unroll
    for (int r = 0; r < 4; ++r) {
        ssp[r] += __shfl_xor(ssp[r], 1);
        ssp[r] += __shfl_xor(ssp[r], 2);
        ssp[r] += __shfl_xor(ssp[r], 4);
        ssp[r] += __shfl_xor(ssp[r], 8);
    }
    if (m16 == 0) {
        #pragma unroll
        for (int r = 0; r < 4; ++r) ssh[rh * 16 + quad * 4 + r][ch] = ssp[r];
    }
    __syncthreads();

    #pragma unroll
    for (int r = 0; r < 4; ++r) {
        int rowl = rh * 16 + quad * 4 + r;
        long rowg = row0 + rowl;
        float ss = ssh[rowl][0] + ssh[rowl][1];
        float scale = 1.0f / fmaxf(sqrtf(ss), 1e-12f);
        if (isq) {
            scale *= (float)mask_q[rowg];
            #pragma unroll
            for (int cti = 0; cti < 4; ++cti)
                q_repr[rowg * DIM + (ch * 4 + cti) * 16 + m16] = vv[cti][r] * scale;
        } else {
            scale *= (float)mask_d[rowg];   // masked rows -> zero vector
            #pragma unroll
            for (int cti = 0; cti < 4; ++cti)
                d_repr[rowg * DIM + (ch * 4 + cti) * 16 + m16] = vv[cti][r] * scale;
        }
    }
}

// ---------------------------------------------------------------------------
// Pool: segment-sum via LDS accumulation. Block = (b, 16-dim chunk), 128
// blocks. acc[513][17] (pad 17 -> bank (17*seg+j)&31 spread for random segs).
// Masked rows were stored as zeros, so unconditional add is correct.
// Writes ALL MAXK segs -> no memset of sums needed.
__global__ __launch_bounds__(256) void pool_kernel(
    const float* __restrict__ d_repr,   // [B*LD][DIM]
    const int*   __restrict__ labels,   // [B*LD]
    const int*   __restrict__ kvals,    // [B]
    float*       __restrict__ sums)     // [B][MAXK][DIM]
{
    __shared__ float acc[MAXK][17];     // 34884 B

    const int b  = blockIdx.x >> 3;
    const int dc = (blockIdx.x & 7) * 16;
    const int t  = threadIdx.x;

    for (int i = t; i < MAXK * 17; i += 256) (&acc[0][0])[i] = 0.f;
    __syncthreads();

    const int kb = kvals[b];
    #pragma unroll
    for (int i = 0; i < LD / 256; ++i) {
        const int row = i * 256 + t;
        const long g = (long)b * LD + row;
        const int seg = labels[g] % kb;
        const float* p = d_repr + g * DIM + dc;
        #pragma unroll
        for (int j = 0; j < 4; ++j) {
            float4 v = *(const float4*)(p + j * 4);
            atomicAdd(&acc[seg][j * 4 + 0], v.x);
            atomicAdd(&acc[seg][j * 4 + 1], v.y);
            atomicAdd(&acc[seg][j * 4 + 2], v.z);
            atomicAdd(&acc[seg][j * 4 + 3], v.w);
        }
    }
    __syncthreads();

    for (int i = t; i < MAXK * 16; i += 256) {
        const int seg = i >> 4, j = i & 15;
        sums[((long)b * MAXK + seg) * DIM + dc + j] = acc[seg][j];
    }
}

// ---------------------------------------------------------------------------
// Sim via MFMA: block = (b, 64-cluster chunk). Stage Q (split bf16) and C
// (rounded bf16) in LDS, 16x16x32 MFMA over K=DIM=128, normalize(sum) trick
// via per-cluster rsqrt, shuffle-max over clusters -> pmax[b][chunk][64].
__global__ __launch_bounds__(256) void simmax_kernel(
    const float* __restrict__ q_repr,   // [B][LQ][DIM]
    const float* __restrict__ sums,     // [B][MAXK][DIM] raw cluster sums
    const int*   __restrict__ kvals,
    float*       __restrict__ pmax)     // [B][SCH][64]
{
    __shared__ __align__(16) ushort Qh[64 * 136];
    __shared__ __align__(16) ushort Ql[64 * 136];
    __shared__ __align__(16) ushort Ch[64 * 136];
    __shared__ float cn[64];

    int b = blockIdx.x / SCH, chunk = blockIdx.x % SCH;
    int t = threadIdx.x, w = t >> 6, lane = t & 63;
    int m16 = lane & 15, quad = lane >> 4;

    // stage Q (64 rows x 128), split hi/lo
    #pragma unroll
    for (int i = 0; i < 8; ++i) {
        int flat = i * 256 + t;          // float4 index
        int row = flat >> 5, c4 = flat & 31;
        float4 v = *(const float4*)(q_repr + ((long)b * LQ + row) * DIM + c4 * 4);
        float x[4]; *(float4*)x = v;
        ushort4 h, l;
        ushort* hp = (ushort*)&h; ushort* lp = (ushort*)&l;
        #pragma unroll
        for (int j = 0; j < 4; ++j) {
            unsigned int ux = __float_as_uint(x[j]);
            hp[j] = (ushort)(ux >> 16);
            lp[j] = f2b_rn(x[j] - __uint_as_float(ux & 0xffff0000u));
        }
        *(ushort4*)&Qh[row * 136 + c4 * 4] = h;
        *(ushort4*)&Ql[row * 136 + c4 * 4] = l;
    }
    // stage C (64 clusters x 128), rounded bf16
    #pragma unroll
    for (int i = 0; i < 8; ++i) {
        int flat = i * 256 + t;
        int row = flat >> 5, c4 = flat & 31;
        int kk = chunk * 64 + row;
        float4 v = (kk < MAXK)
            ? *(const float4*)(sums + ((long)b * MAXK + kk) * DIM + c4 * 4)
            : make_float4(0.f, 0.f, 0.f, 0.f);
        ushort4 h; ushort* hp = (ushort*)&h;
        hp[0] = f2b_rn(v.x); hp[1] = f2b_rn(v.y);
        hp[2] = f2b_rn(v.z); hp[3] = f2b_rn(v.w);
        *(ushort4*)&Ch[row * 136 + c4 * 4] = h;
    }
    __syncthreads();

    // per-cluster inv-norms from staged C (quad-split over d, shuffle-combine)
    {
        int c = w * 16 + m16;
        float ssv = 0.f;
        #pragma unroll
        for (int j = 0; j < 16; ++j) {
            unsigned int u = *(const unsigned int*)&Ch[c * 136 + quad * 32 + j * 2];
            float x0 = b2f((ushort)u), x1 = b2f((ushort)(u >> 16));
            ssv += x0 * x0 + x1 * x1;
        }
        ssv += __shfl_xor(ssv, 16);
        ssv += __shfl_xor(ssv, 32);
        if (quad == 0) cn[c] = (ssv > 1e-24f) ? rsqrtf(ssv) : 0.f;
    }
    __syncthreads();

    // MFMA: wave w -> q rows [w*16, w*16+16), all 64 clusters (4 ct tiles)
    f32x4 acc[4];
    #pragma unroll
    for (int j = 0; j < 4; ++j) acc[j] = (f32x4){0.f, 0.f, 0.f, 0.f};

    #pragma unroll
    for (int kc = 0; kc < 4; ++kc) {
        short8 qh = *(const short8*)&Qh[(w * 16 + m16) * 136 + kc * 32 + quad * 8];
        short8 ql = *(const short8*)&Ql[(w * 16 + m16) * 136 + kc * 32 + quad * 8];
        #pragma unroll
        for (int ct = 0; ct < 4; ++ct) {
            short8 cf = *(const short8*)&Ch[(ct * 16 + m16) * 136 + kc * 32 + quad * 8];
            acc[ct] = __builtin_amdgcn_mfma_f32_16x16x32_bf16(qh, cf, acc[ct], 0, 0, 0);
            acc[ct] = __builtin_amdgcn_mfma_f32_16x16x32_bf16(ql, cf, acc[ct], 0, 0, 0);
        }
    }

    int kb = kvals[b];
    #pragma unroll
    for (int r = 0; r < 4; ++r) {
        float mx = -1e4f;
        #pragma unroll
        for (int ct = 0; ct < 4; ++ct) {
            int cl = chunk * 64 + ct * 16 + m16;
            float sim = acc[ct][r] * cn[ct * 16 + m16];
            mx = fmaxf(mx, (cl < kb) ? sim : -1e4f);
        }
        mx = fmaxf(mx, __shfl_xor(mx, 1));
        mx = fmaxf(mx, __shfl_xor(mx, 2));
        mx = fmaxf(mx, __shfl_xor(mx, 4));
        mx = fmaxf(mx, __shfl_xor(mx, 8));
        if (m16 == 0)
            pmax[((long)b * SCH + chunk) * 64 + w * 16 + quad * 4 + r] = mx;
    }
}

// ---------------------------------------------------------------------------
// Final: per batch, max over chunks, *q_mask, sum over rows -> out[b]
__global__ __launch_bounds__(64) void final_kernel(
    const float* __restrict__ pmax,
    const int*   __restrict__ q_mask,
    float*       __restrict__ out)
{
    int b = blockIdx.x, r = threadIdx.x;
    float m = -3e38f;
    #pragma unroll
    for (int c = 0; c < SCH; ++c)
        m = fmaxf(m, pmax[((long)b * SCH + c) * 64 + r]);
    m *= (float)q_mask[b * LQ + r];
    #pragma unroll
    for (int sh = 1; sh < 64; sh <<= 1) m += __shfl_xor(m, sh);
    if (r == 0) out[b] = m;
}

// ---------------------------------------------------------------------------
extern "C" void kernel_launch(void* const* d_in, const int* in_sizes, int n_in,
                              void* d_out, int out_size, void* d_ws, size_t ws_size,
                              hipStream_t stream) {
    const float* q_hidden = (const float*)d_in[0];
    const float* d_hidden = (const float*)d_in[1];
    const float* W        = (const float*)d_in[2];
    const float* bias     = (const float*)d_in[3];
    const int*   q_mask   = (const int*)d_in[4];
    const int*   d_mask   = (const int*)d_in[5];
    const int*   labels   = (const int*)d_in[6];
    const int*   pf       = (const int*)d_in[7];

    float* ws     = (float*)d_ws;
    float* q_repr = ws;                                   // 131,072 f
    float* sums   = q_repr + (long)BB * LQ * DIM;         // 1,050,624 f
    float* pmaxb  = sums + (long)BB * MAXK * DIM;         // 16*9*64 = 9,216 f
    int*   kvals  = (int*)(pmaxb + BB * SCH * 64);        // 16
    ushort* Wt    = (ushort*)(kvals + 16);                // 131,072 bf16
    float* d_repr = (float*)(Wt + (long)HH * DIM);        // 4,194,304 f (16.8 MB)

    prep_kb_kernel<<<512 + BB, 256, 0, stream>>>(W, d_mask, pf, Wt, kvals);
    encode_kernel<<<DGRID + QGRID, 256, 0, stream>>>(d_hidden, q_hidden, Wt, bias,
                                                     d_mask, q_mask, d_repr, q_repr);
    pool_kernel<<<BB * 8, 256, 0, stream>>>(d_repr, labels, kvals, sums);
    simmax_kernel<<<BB * SCH, 256, 0, stream>>>(q_repr, sums, kvals, pmaxb);
    final_kernel<<<BB, 64, 0, stream>>>(pmaxb, q_mask, (float*)d_out);
}

// Round 2
// 265.880 us; speedup vs baseline: 1.1175x; 1.1175x over previous
//
#include <hip/hip_runtime.h>
#include <hip/hip_bf16.h>

// Problem constants (from reference)
#define BB    16
#define LQ    64
#define LD    2048
#define HH    1024
#define DIM   128
#define MAXK  513          // LD/PF + 1 with PF=4
#define SCH   9            // ceil(513/64) cluster chunks for simmax
#define DGRID 1024         // d-encode blocks (32768 / 32)
#define QGRID 32           // q-encode blocks (1024 / 32)

typedef __attribute__((ext_vector_type(8))) short short8;
typedef __attribute__((ext_vector_type(4))) float f32x4;

__device__ __forceinline__ float b2f(ushort u) {
    union { float f; unsigned int u32; } c; c.u32 = ((unsigned int)u) << 16; return c.f;
}
__device__ __forceinline__ ushort f2b_rn(float f) {
    unsigned int x = __float_as_uint(f);
    return (ushort)((x + 0x7fffu + ((x >> 16) & 1u)) >> 16);
}

// async global->LDS, 16B/lane; LDS dest = wave-uniform base + lane*16
__device__ __forceinline__ void gld16(void* lds, const void* g) {
    __builtin_amdgcn_global_load_lds(
        (const __attribute__((address_space(1))) unsigned int*)g,
        (__attribute__((address_space(3))) unsigned int*)lds,
        16, 0, 0);
}

// ---------------------------------------------------------------------------
// Fused prep:
//   blocks [0,16):   LDS-tile transpose+round W -> Wt bf16 (coalesced writes)
//   blocks [16,32):  kvals per batch
//   blocks [32,288): zero sums (replaces hipMemsetAsync dispatch)
__global__ __launch_bounds__(256) void prep_kb_kernel(
    const float* __restrict__ W,
    const int*   __restrict__ d_mask,
    const int*   __restrict__ pf,
    ushort*      __restrict__ Wt,
    int*         __restrict__ kvals,
    float*       __restrict__ sums)
{
    int bid = blockIdx.x, t = threadIdx.x;
    if (bid < 16) {
        // transpose 64 h-rows x 128 n-cols per block
        __shared__ ushort tile[128][72];   // stride 72 ushorts = 144B (16B-mult)
        const int h0 = bid * 64;
        #pragma unroll
        for (int i = 0; i < 32; ++i) {     // 64*128/256
            int flat = i * 256 + t;
            int r = flat >> 7, c = flat & 127;
            tile[c][r] = f2b_rn(W[(long)(h0 + r) * DIM + c]);
        }
        __syncthreads();
        #pragma unroll
        for (int i = 0; i < 4; ++i) {      // 128 rows x 8 uint4 = 1024 uint4
            int flat = i * 256 + t;
            int n = flat >> 3, u = flat & 7;
            uint4 v = *(const uint4*)&tile[n][u * 8];
            *(uint4*)&Wt[(long)n * HH + h0 + u * 8] = v;
        }
    } else if (bid < 32) {
        __shared__ int red[4];
        int b = bid - 16;
        int lane = t & 63, wave = t >> 6;
        int s = 0;
        for (int i = t; i < LD; i += 256) s += (d_mask[b * LD + i] > 0) ? 1 : 0;
        #pragma unroll
        for (int m = 1; m < 64; m <<= 1) s += __shfl_xor(s, m);
        if (lane == 0) red[wave] = s;
        __syncthreads();
        if (t == 0) {
            int v = red[0] + red[1] + red[2] + red[3];
            if (v < 2) v = 2;
            int pfv = pf[0];
            if (pfv < 1 || pfv > LD) pfv = 4;   // defensive
            kvals[b] = v / pfv + 1;
        }
    } else {
        // zero sums: BB*MAXK*DIM = 1,050,624 floats = 262,656 float4
        const int total4 = (BB * MAXK * DIM) / 4;
        float4* s4 = (float4*)sums;
        const float4 z = make_float4(0.f, 0.f, 0.f, 0.f);
        for (int i = (bid - 32) * 256 + t; i < total4; i += 256 * 256)
            s4[i] = z;
    }
}

// ---------------------------------------------------------------------------
// Encode + fused pooled-scatter.
// 32-row x 128-col tile, 256 threads = 4 waves: wave w -> rows (w&1)*16,
// ct-group (w>>1)*4. BK=32. Counted-vmcnt pipeline (T3/T4): 4 LDS buffers,
// prefetch depth 3; per chunk: s_waitcnt vmcnt(6) + raw s_barrier (6 loads
// stay in flight across every barrier -- NO vmcnt(0) drain in the loop;
// the old __syncthreads drained the prefetch issued only ~1 chunk of compute
// earlier, eating ~full load latency x32 chunks).
// LDS units of 16B/buffer: A = [0,256): 32 rows x 8 units (fp32, xor row&7);
// B = [256,768): 128 rows x 4 units (bf16, xor (row>>2)&3).
// 2 MFMA passes: A split hi+lo (exact), W rounded bf16.
__global__ __launch_bounds__(256, 3) void encode_kernel(
    const float*  __restrict__ Xd,      // [32768][H]
    const float*  __restrict__ Xq,      // [1024][H]
    const ushort* __restrict__ Wt,      // [DIM][H] bf16 rounded
    const float*  __restrict__ bias,    // [DIM]
    const int*    __restrict__ mask_d,  // [32768]
    const int*    __restrict__ mask_q,  // [1024]
    const int*    __restrict__ labels,  // [32768]
    const int*    __restrict__ kvals,   // [BB]
    float*        __restrict__ sums,    // [BB][MAXK][DIM]
    float*        __restrict__ q_repr)  // [1024][DIM]
{
    __shared__ __align__(16) uint4 buf[4][768];   // 48 KB
    __shared__ float ssh[32][2];

    const int bid = blockIdx.x;
    const bool isq = bid >= DGRID;
    const float* X = isq ? Xq : Xd;
    const long row0 = isq ? (long)(bid - DGRID) * 32 : (long)bid * 32;

    const int t = threadIdx.x;
    const int w = t >> 6, lane = t & 63;
    const int m16 = lane & 15, quad = lane >> 4;
    const int rh = w & 1, ch = w >> 1;

    // staging sources (per lane), advance 32 elements per chunk
    const float*  gA  = X + (row0 + w * 8 + (lane >> 3)) * HH
                          + (((lane & 7) ^ ((lane >> 3) & 7)) * 4);
    const ushort* gB0 = Wt + (long)(w * 32 + (lane >> 2)) * HH
                           + (((lane & 3) ^ ((lane >> 4) & 3)) * 8);
    const ushort* gB1 = gB0 + 16 * HH;

    f32x4 acc[4];
    #pragma unroll
    for (int j = 0; j < 4; ++j) acc[j] = (f32x4){0.f, 0.f, 0.f, 0.f};

    // prologue: stage chunks 0..2 (9 loads outstanding per wave)
    #pragma unroll
    for (int p = 0; p < 3; ++p) {
        const int ko = p * 32;
        gld16(&buf[p][w * 64], gA + ko);
        gld16(&buf[p][256 + w * 128], gB0 + ko);
        gld16(&buf[p][256 + w * 128 + 64], gB1 + ko);
    }

    const int sw = m16 & 7;
    const int bsw = m16 >> 2;
    const int au = (rh * 16 + m16) * 8;

    auto compute = [&](int cur) {
        float4 va0 = *(const float4*)&buf[cur][au + ((2 * quad) ^ sw)];
        float4 va1 = *(const float4*)&buf[cur][au + ((2 * quad + 1) ^ sw)];
        float av[8];
        *(float4*)(av) = va0; *(float4*)(av + 4) = va1;
        short8 ah, al;
        #pragma unroll
        for (int j = 0; j < 8; ++j) {
            unsigned int ux = __float_as_uint(av[j]);
            ah[j] = (short)(ux >> 16);
            float hif = __uint_as_float(ux & 0xffff0000u);
            al[j] = (short)(__float_as_uint(av[j] - hif) >> 16);
        }
        #pragma unroll
        for (int cti = 0; cti < 4; ++cti) {
            const int ct = ch * 4 + cti;
            short8 bf = *(const short8*)&buf[cur][256 + (ct * 16 + m16) * 4 + (quad ^ bsw)];
            acc[cti] = __builtin_amdgcn_mfma_f32_16x16x32_bf16(ah, bf, acc[cti], 0, 0, 0);
            acc[cti] = __builtin_amdgcn_mfma_f32_16x16x32_bf16(al, bf, acc[cti], 0, 0, 0);
        }
    };

    // main loop: chunks 0..28; S(c) guaranteed by vmcnt(6) (6 newer in flight)
    for (int c = 0; c < 29; ++c) {
        asm volatile("s_waitcnt vmcnt(6)" ::: "memory");
        __builtin_amdgcn_s_barrier();
        __builtin_amdgcn_sched_barrier(0);
        const int nxt = (c + 3) & 3;
        const int ko = (c + 3) * 32;
        gld16(&buf[nxt][w * 64], gA + ko);
        gld16(&buf[nxt][256 + w * 128], gB0 + ko);
        gld16(&buf[nxt][256 + w * 128 + 64], gB1 + ko);
        compute(c & 3);
    }
    // tail: chunks 29,30,31 (outstanding 9 -> 6 -> 3)
    asm volatile("s_waitcnt vmcnt(6)" ::: "memory");
    __builtin_amdgcn_s_barrier();
    __builtin_amdgcn_sched_barrier(0);
    compute(1);
    asm volatile("s_waitcnt vmcnt(3)" ::: "memory");
    __builtin_amdgcn_s_barrier();
    __builtin_amdgcn_sched_barrier(0);
    compute(2);
    asm volatile("s_waitcnt vmcnt(0)" ::: "memory");
    __builtin_amdgcn_s_barrier();
    __builtin_amdgcn_sched_barrier(0);
    compute(3);

    // epilogue: bias, cross-wave row norm (cols split across ch), mask, scatter
    float bia[4];
    #pragma unroll
    for (int cti = 0; cti < 4; ++cti) bia[cti] = bias[(ch * 4 + cti) * 16 + m16];

    float vv[4][4];
    float ssp[4] = {0.f, 0.f, 0.f, 0.f};
    #pragma unroll
    for (int cti = 0; cti < 4; ++cti)
        #pragma unroll
        for (int r = 0; r < 4; ++r) {
            vv[cti][r] = acc[cti][r] + bia[cti];
            ssp[r] += vv[cti][r] * vv[cti][r];
        }
    #pragma unroll
    for (int r = 0; r < 4; ++r) {
        ssp[r] += __shfl_xor(ssp[r], 1);
        ssp[r] += __shfl_xor(ssp[r], 2);
        ssp[r] += __shfl_xor(ssp[r], 4);
        ssp[r] += __shfl_xor(ssp[r], 8);
    }
    if (m16 == 0) {
        #pragma unroll
        for (int r = 0; r < 4; ++r) ssh[rh * 16 + quad * 4 + r][ch] = ssp[r];
    }
    __syncthreads();

    #pragma unroll
    for (int r = 0; r < 4; ++r) {
        int rowl = rh * 16 + quad * 4 + r;
        long rowg = row0 + rowl;
        float ss = ssh[rowl][0] + ssh[rowl][1];
        float scale = 1.0f / fmaxf(sqrtf(ss), 1e-12f);
        if (isq) {
            scale *= (float)mask_q[rowg];
            #pragma unroll
            for (int cti = 0; cti < 4; ++cti)
                q_repr[rowg * DIM + (ch * 4 + cti) * 16 + m16] = vv[cti][r] * scale;
        } else if (mask_d[rowg] > 0) {
            int b = (int)(rowg >> 11);
            int seg = labels[rowg] % kvals[b];
            float* sp = sums + ((long)b * MAXK + seg) * DIM + m16;
            #pragma unroll
            for (int cti = 0; cti < 4; ++cti)
                atomicAdd(sp + (ch * 4 + cti) * 16, vv[cti][r] * scale);
        }
    }
}

// ---------------------------------------------------------------------------
// Sim via MFMA: block = (b, 64-cluster chunk). Stage Q (split bf16) and C
// (rounded bf16) in LDS, 16x16x32 MFMA over K=DIM=128, normalize(sum) trick
// via per-cluster rsqrt, shuffle-max over clusters -> pmax[b][chunk][64].
__global__ __launch_bounds__(256) void simmax_kernel(
    const float* __restrict__ q_repr,   // [B][LQ][DIM]
    const float* __restrict__ sums,     // [B][MAXK][DIM] raw cluster sums
    const int*   __restrict__ kvals,
    float*       __restrict__ pmax)     // [B][SCH][64]
{
    __shared__ __align__(16) ushort Qh[64 * 136];
    __shared__ __align__(16) ushort Ql[64 * 136];
    __shared__ __align__(16) ushort Ch[64 * 136];
    __shared__ float cn[64];

    int b = blockIdx.x / SCH, chunk = blockIdx.x % SCH;
    int t = threadIdx.x, w = t >> 6, lane = t & 63;
    int m16 = lane & 15, quad = lane >> 4;

    // stage Q (64 rows x 128), split hi/lo
    #pragma unroll
    for (int i = 0; i < 8; ++i) {
        int flat = i * 256 + t;          // float4 index
        int row = flat >> 5, c4 = flat & 31;
        float4 v = *(const float4*)(q_repr + ((long)b * LQ + row) * DIM + c4 * 4);
        float x[4]; *(float4*)x = v;
        ushort4 h, l;
        ushort* hp = (ushort*)&h; ushort* lp = (ushort*)&l;
        #pragma unroll
        for (int j = 0; j < 4; ++j) {
            unsigned int ux = __float_as_uint(x[j]);
            hp[j] = (ushort)(ux >> 16);
            lp[j] = f2b_rn(x[j] - __uint_as_float(ux & 0xffff0000u));
        }
        *(ushort4*)&Qh[row * 136 + c4 * 4] = h;
        *(ushort4*)&Ql[row * 136 + c4 * 4] = l;
    }
    // stage C (64 clusters x 128), rounded bf16
    #pragma unroll
    for (int i = 0; i < 8; ++i) {
        int flat = i * 256 + t;
        int row = flat >> 5, c4 = flat & 31;
        int kk = chunk * 64 + row;
        float4 v = (kk < MAXK)
            ? *(const float4*)(sums + ((long)b * MAXK + kk) * DIM + c4 * 4)
            : make_float4(0.f, 0.f, 0.f, 0.f);
        ushort4 h; ushort* hp = (ushort*)&h;
        hp[0] = f2b_rn(v.x); hp[1] = f2b_rn(v.y);
        hp[2] = f2b_rn(v.z); hp[3] = f2b_rn(v.w);
        *(ushort4*)&Ch[row * 136 + c4 * 4] = h;
    }
    __syncthreads();

    // per-cluster inv-norms from staged C (quad-split over d, shuffle-combine)
    {
        int c = w * 16 + m16;
        float ssv = 0.f;
        #pragma unroll
        for (int j = 0; j < 16; ++j) {
            unsigned int u = *(const unsigned int*)&Ch[c * 136 + quad * 32 + j * 2];
            float x0 = b2f((ushort)u), x1 = b2f((ushort)(u >> 16));
            ssv += x0 * x0 + x1 * x1;
        }
        ssv += __shfl_xor(ssv, 16);
        ssv += __shfl_xor(ssv, 32);
        if (quad == 0) cn[c] = (ssv > 1e-24f) ? rsqrtf(ssv) : 0.f;
    }
    __syncthreads();

    // MFMA: wave w -> q rows [w*16, w*16+16), all 64 clusters (4 ct tiles)
    f32x4 acc[4];
    #pragma unroll
    for (int j = 0; j < 4; ++j) acc[j] = (f32x4){0.f, 0.f, 0.f, 0.f};

    #pragma unroll
    for (int kc = 0; kc < 4; ++kc) {
        short8 qh = *(const short8*)&Qh[(w * 16 + m16) * 136 + kc * 32 + quad * 8];
        short8 ql = *(const short8*)&Ql[(w * 16 + m16) * 136 + kc * 32 + quad * 8];
        #pragma unroll
        for (int ct = 0; ct < 4; ++ct) {
            short8 cf = *(const short8*)&Ch[(ct * 16 + m16) * 136 + kc * 32 + quad * 8];
            acc[ct] = __builtin_amdgcn_mfma_f32_16x16x32_bf16(qh, cf, acc[ct], 0, 0, 0);
            acc[ct] = __builtin_amdgcn_mfma_f32_16x16x32_bf16(ql, cf, acc[ct], 0, 0, 0);
        }
    }

    int kb = kvals[b];
    #pragma unroll
    for (int r = 0; r < 4; ++r) {
        float mx = -1e4f;
        #pragma unroll
        for (int ct = 0; ct < 4; ++ct) {
            int cl = chunk * 64 + ct * 16 + m16;
            float sim = acc[ct][r] * cn[ct * 16 + m16];
            mx = fmaxf(mx, (cl < kb) ? sim : -1e4f);
        }
        mx = fmaxf(mx, __shfl_xor(mx, 1));
        mx = fmaxf(mx, __shfl_xor(mx, 2));
        mx = fmaxf(mx, __shfl_xor(mx, 4));
        mx = fmaxf(mx, __shfl_xor(mx, 8));
        if (m16 == 0)
            pmax[((long)b * SCH + chunk) * 64 + w * 16 + quad * 4 + r] = mx;
    }
}

// ---------------------------------------------------------------------------
// Final: per batch, max over chunks, *q_mask, sum over rows -> out[b]
__global__ __launch_bounds__(64) void final_kernel(
    const float* __restrict__ pmax,
    const int*   __restrict__ q_mask,
    float*       __restrict__ out)
{
    int b = blockIdx.x, r = threadIdx.x;
    float m = -3e38f;
    #pragma unroll
    for (int c = 0; c < SCH; ++c)
        m = fmaxf(m, pmax[((long)b * SCH + c) * 64 + r]);
    m *= (float)q_mask[b * LQ + r];
    #pragma unroll
    for (int sh = 1; sh < 64; sh <<= 1) m += __shfl_xor(m, sh);
    if (r == 0) out[b] = m;
}

// ---------------------------------------------------------------------------
extern "C" void kernel_launch(void* const* d_in, const int* in_sizes, int n_in,
                              void* d_out, int out_size, void* d_ws, size_t ws_size,
                              hipStream_t stream) {
    const float* q_hidden = (const float*)d_in[0];
    const float* d_hidden = (const float*)d_in[1];
    const float* W        = (const float*)d_in[2];
    const float* bias     = (const float*)d_in[3];
    const int*   q_mask   = (const int*)d_in[4];
    const int*   d_mask   = (const int*)d_in[5];
    const int*   labels   = (const int*)d_in[6];
    const int*   pf       = (const int*)d_in[7];

    float* ws     = (float*)d_ws;
    float* q_repr = ws;                                   // 131,072 f
    float* sums   = q_repr + (long)BB * LQ * DIM;         // 1,050,624 f
    float* pmaxb  = sums + (long)BB * MAXK * DIM;         // 16*9*64 = 9,216 f
    int*   kvals  = (int*)(pmaxb + BB * SCH * 64);        // 16
    ushort* Wt    = (ushort*)(kvals + 16);                // 131,072 bf16

    prep_kb_kernel<<<288, 256, 0, stream>>>(W, d_mask, pf, Wt, kvals, sums);
    encode_kernel<<<DGRID + QGRID, 256, 0, stream>>>(d_hidden, q_hidden, Wt, bias,
                                                     d_mask, q_mask, labels, kvals,
                                                     sums, q_repr);
    simmax_kernel<<<BB * SCH, 256, 0, stream>>>(q_repr, sums, kvals, pmaxb);
    final_kernel<<<BB, 64, 0, stream>>>(pmaxb, q_mask, (float*)d_out);
}

// Round 3
// 254.856 us; speedup vs baseline: 1.1658x; 1.0433x over previous
//
#include <hip/hip_runtime.h>
#include <hip/hip_bf16.h>

// Problem constants (from reference)
#define BB    16
#define LQ    64
#define LD    2048
#define HH    1024
#define DIM   128
#define MAXK  513          // LD/PF + 1 with PF=4
#define SCH   9            // ceil(513/64) cluster chunks for simmax
#define DGRID 512          // d-encode blocks (32768 / 64)
#define QGRID 16           // q-encode blocks (1024 / 64)

typedef __attribute__((ext_vector_type(8))) short short8;
typedef __attribute__((ext_vector_type(4))) float f32x4;

__device__ __forceinline__ float b2f(ushort u) {
    union { float f; unsigned int u32; } c; c.u32 = ((unsigned int)u) << 16; return c.f;
}
__device__ __forceinline__ ushort f2b_rn(float f) {
    unsigned int x = __float_as_uint(f);
    return (ushort)((x + 0x7fffu + ((x >> 16) & 1u)) >> 16);
}

// async global->LDS, 16B/lane; LDS dest = wave-uniform base + lane*16
__device__ __forceinline__ void gld16(void* lds, const void* g) {
    __builtin_amdgcn_global_load_lds(
        (const __attribute__((address_space(1))) unsigned int*)g,
        (__attribute__((address_space(3))) unsigned int*)lds,
        16, 0, 0);
}

// ---------------------------------------------------------------------------
// Fused prep:
//   blocks [0,16):   LDS-tile transpose+round W -> Wt bf16 (coalesced writes)
//   blocks [16,32):  kvals per batch
//   blocks [32,288): zero sums (replaces hipMemsetAsync dispatch)
__global__ __launch_bounds__(256) void prep_kb_kernel(
    const float* __restrict__ W,
    const int*   __restrict__ d_mask,
    const int*   __restrict__ pf,
    ushort*      __restrict__ Wt,
    int*         __restrict__ kvals,
    float*       __restrict__ sums)
{
    int bid = blockIdx.x, t = threadIdx.x;
    if (bid < 16) {
        // transpose 64 h-rows x 128 n-cols per block
        __shared__ ushort tile[128][72];   // stride 72 ushorts = 144B (16B-mult)
        const int h0 = bid * 64;
        #pragma unroll
        for (int i = 0; i < 32; ++i) {     // 64*128/256
            int flat = i * 256 + t;
            int r = flat >> 7, c = flat & 127;
            tile[c][r] = f2b_rn(W[(long)(h0 + r) * DIM + c]);
        }
        __syncthreads();
        #pragma unroll
        for (int i = 0; i < 4; ++i) {      // 128 rows x 8 uint4 = 1024 uint4
            int flat = i * 256 + t;
            int n = flat >> 3, u = flat & 7;
            uint4 v = *(const uint4*)&tile[n][u * 8];
            *(uint4*)&Wt[(long)n * HH + h0 + u * 8] = v;
        }
    } else if (bid < 32) {
        __shared__ int red[4];
        int b = bid - 16;
        int lane = t & 63, wave = t >> 6;
        int s = 0;
        for (int i = t; i < LD; i += 256) s += (d_mask[b * LD + i] > 0) ? 1 : 0;
        #pragma unroll
        for (int m = 1; m < 64; m <<= 1) s += __shfl_xor(s, m);
        if (lane == 0) red[wave] = s;
        __syncthreads();
        if (t == 0) {
            int v = red[0] + red[1] + red[2] + red[3];
            if (v < 2) v = 2;
            int pfv = pf[0];
            if (pfv < 1 || pfv > LD) pfv = 4;   // defensive
            kvals[b] = v / pfv + 1;
        }
    } else {
        // zero sums: BB*MAXK*DIM = 1,050,624 floats = 262,656 float4
        const int total4 = (BB * MAXK * DIM) / 4;
        float4* s4 = (float4*)sums;
        const float4 z = make_float4(0.f, 0.f, 0.f, 0.f);
        for (int i = (bid - 32) * 256 + t; i < total4; i += 256 * 256)
            s4[i] = z;
    }
}

// ---------------------------------------------------------------------------
// Encode + fused pooled-scatter. TM=64 tile, 512 threads = 8 waves.
// Wave w: rh=w&3 (16-row group), ch=w>>2 (64-col half). BK=32, 32 chunks.
// 3 LDS buffers, prefetch depth 2, counted vmcnt(2) per chunk (2 gld16/wave
// per chunk -> vmcnt(2) = current chunk landed, next chunk stays in flight).
// vs round-2 failure: same 48.5KB LDS as the depth-3/256-thread variant but
// 8 waves/block -> 16-24 waves/CU (was 7.5); B(Wt) L2 traffic halved vs TM=32.
// LDS units of 16B/buffer: A = [0,512): 64 rows x 8 units (fp32, xor row&7);
// B = [512,1024): 128 rows x 4 units (bf16, xor (row>>2)&3).
// 2 MFMA passes: A split hi+lo (exact), W rounded bf16.
__global__ __launch_bounds__(512, 6) void encode_kernel(
    const float*  __restrict__ Xd,      // [32768][H]
    const float*  __restrict__ Xq,      // [1024][H]
    const ushort* __restrict__ Wt,      // [DIM][H] bf16 rounded
    const float*  __restrict__ bias,    // [DIM]
    const int*    __restrict__ mask_d,  // [32768]
    const int*    __restrict__ mask_q,  // [1024]
    const int*    __restrict__ labels,  // [32768]
    const int*    __restrict__ kvals,   // [BB]
    float*        __restrict__ sums,    // [BB][MAXK][DIM]
    float*        __restrict__ q_repr)  // [1024][DIM]
{
    __shared__ __align__(16) uint4 buf[3][1024];   // 48 KB
    __shared__ float ssh[64][2];

    const int bid = blockIdx.x;
    const bool isq = bid >= DGRID;
    const float* X = isq ? Xq : Xd;
    const long row0 = isq ? (long)(bid - DGRID) * 64 : (long)bid * 64;

    const int t = threadIdx.x;
    const int w = t >> 6, lane = t & 63;
    const int m16 = lane & 15, quad = lane >> 4;
    const int rh = w & 3, ch = w >> 2;

    // staging sources (per lane), advance 32 elements per chunk.
    // A: wave stages rows w*8..w*8+7, 8x16B units/row, col-unit xor row&7.
    const float*  gA = X + (row0 + w * 8 + (lane >> 3)) * HH
                         + (((lane & 7) ^ ((lane >> 3) & 7)) * 4);
    // B: wave stages Wt rows w*16..w*16+15, 4x16B units/row, unit xor (row>>2)&3.
    const ushort* gB = Wt + (long)(w * 16 + (lane >> 2)) * HH
                          + (((lane & 3) ^ ((lane >> 4) & 3)) * 8);

    const int wA = w * 64;           // A LDS unit base for this wave
    const int wB = 512 + w * 64;     // B LDS unit base

    f32x4 acc[4];
    #pragma unroll
    for (int j = 0; j < 4; ++j) acc[j] = (f32x4){0.f, 0.f, 0.f, 0.f};

    // prologue: stage chunks 0,1 (4 loads outstanding per wave)
    gld16(&buf[0][wA], gA);
    gld16(&buf[0][wB], gB);
    gld16(&buf[1][wA], gA + 32);
    gld16(&buf[1][wB], gB + 32);

    const int sw = m16 & 7;
    const int bsw = m16 >> 2;
    const int au = (rh * 16 + m16) * 8;

    auto compute = [&](const uint4* bb) {
        float4 va0 = *(const float4*)&bb[au + ((2 * quad) ^ sw)];
        float4 va1 = *(const float4*)&bb[au + ((2 * quad + 1) ^ sw)];
        float av[8];
        *(float4*)(av) = va0; *(float4*)(av + 4) = va1;
        short8 ah, al;
        #pragma unroll
        for (int j = 0; j < 8; ++j) {
            unsigned int ux = __float_as_uint(av[j]);
            ah[j] = (short)(ux >> 16);
            float hif = __uint_as_float(ux & 0xffff0000u);
            al[j] = (short)(__float_as_uint(av[j] - hif) >> 16);
        }
        #pragma unroll
        for (int cti = 0; cti < 4; ++cti) {
            const int ct = ch * 4 + cti;
            short8 bf = *(const short8*)&bb[512 + (ct * 16 + m16) * 4 + (quad ^ bsw)];
            acc[cti] = __builtin_amdgcn_mfma_f32_16x16x32_bf16(ah, bf, acc[cti], 0, 0, 0);
            acc[cti] = __builtin_amdgcn_mfma_f32_16x16x32_bf16(al, bf, acc[cti], 0, 0, 0);
        }
    };

    // chunk c lives in buf[c%3]; per iter: wait chunk c (vmcnt(2): chunk c+1
    // stays in flight), barrier, issue chunk c+2 into buf[(c+2)%3] (the
    // buffer compute(c-1) finished with before this barrier), compute c.
    #define STEP(C, CUR, NXT)                                              \
        asm volatile("s_waitcnt vmcnt(2)" ::: "memory");                   \
        __builtin_amdgcn_s_barrier();                                      \
        __builtin_amdgcn_sched_barrier(0);                                 \
        gld16(&buf[NXT][wA], gA + ((C) + 2) * 32);                         \
        gld16(&buf[NXT][wB], gB + ((C) + 2) * 32);                         \
        compute(&buf[CUR][0]);

    for (int c = 0; c < 30; c += 3) {
        STEP(c + 0, 0, 2)
        STEP(c + 1, 1, 0)
        STEP(c + 2, 2, 1)
    }
    #undef STEP
    // tail: chunks 30 (buf0), 31 (buf1); outstanding 4 -> 2 -> 0
    asm volatile("s_waitcnt vmcnt(2)" ::: "memory");
    __builtin_amdgcn_s_barrier();
    __builtin_amdgcn_sched_barrier(0);
    compute(&buf[0][0]);
    asm volatile("s_waitcnt vmcnt(0)" ::: "memory");
    __builtin_amdgcn_s_barrier();
    __builtin_amdgcn_sched_barrier(0);
    compute(&buf[1][0]);

    // epilogue: bias, cross-wave row norm (cols split across ch), mask, scatter
    float bia[4];
    #pragma unroll
    for (int cti = 0; cti < 4; ++cti) bia[cti] = bias[(ch * 4 + cti) * 16 + m16];

    float vv[4][4];
    float ssp[4] = {0.f, 0.f, 0.f, 0.f};
    #pragma unroll
    for (int cti = 0; cti < 4; ++cti)
        #pragma unroll
        for (int r = 0; r < 4; ++r) {
            vv[cti][r] = acc[cti][r] + bia[cti];
            ssp[r] += vv[cti][r] * vv[cti][r];
        }
    #pragma unroll
    for (int r = 0; r < 4; ++r) {
        ssp[r] += __shfl_xor(ssp[r], 1);
        ssp[r] += __shfl_xor(ssp[r], 2);
        ssp[r] += __shfl_xor(ssp[r], 4);
        ssp[r] += __shfl_xor(ssp[r], 8);
    }
    if (m16 == 0) {
        #pragma unroll
        for (int r = 0; r < 4; ++r) ssh[rh * 16 + quad * 4 + r][ch] = ssp[r];
    }
    __syncthreads();

    #pragma unroll
    for (int r = 0; r < 4; ++r) {
        int rowl = rh * 16 + quad * 4 + r;
        long rowg = row0 + rowl;
        float ss = ssh[rowl][0] + ssh[rowl][1];
        float scale = 1.0f / fmaxf(sqrtf(ss), 1e-12f);
        if (isq) {
            scale *= (float)mask_q[rowg];
            #pragma unroll
            for (int cti = 0; cti < 4; ++cti)
                q_repr[rowg * DIM + (ch * 4 + cti) * 16 + m16] = vv[cti][r] * scale;
        } else if (mask_d[rowg] > 0) {
            int b = (int)(rowg >> 11);
            int seg = labels[rowg] % kvals[b];
            float* sp = sums + ((long)b * MAXK + seg) * DIM + m16;
            #pragma unroll
            for (int cti = 0; cti < 4; ++cti)
                atomicAdd(sp + (ch * 4 + cti) * 16, vv[cti][r] * scale);
        }
    }
}

// ---------------------------------------------------------------------------
// Sim via MFMA: block = (b, 64-cluster chunk). Stage Q (split bf16) and C
// (rounded bf16) in LDS, 16x16x32 MFMA over K=DIM=128, normalize(sum) trick
// via per-cluster rsqrt, shuffle-max over clusters -> pmax[b][chunk][64].
__global__ __launch_bounds__(256) void simmax_kernel(
    const float* __restrict__ q_repr,   // [B][LQ][DIM]
    const float* __restrict__ sums,     // [B][MAXK][DIM] raw cluster sums
    const int*   __restrict__ kvals,
    float*       __restrict__ pmax)     // [B][SCH][64]
{
    __shared__ __align__(16) ushort Qh[64 * 136];
    __shared__ __align__(16) ushort Ql[64 * 136];
    __shared__ __align__(16) ushort Ch[64 * 136];
    __shared__ float cn[64];

    int b = blockIdx.x / SCH, chunk = blockIdx.x % SCH;
    int t = threadIdx.x, w = t >> 6, lane = t & 63;
    int m16 = lane & 15, quad = lane >> 4;

    // stage Q (64 rows x 128), split hi/lo
    #pragma unroll
    for (int i = 0; i < 8; ++i) {
        int flat = i * 256 + t;          // float4 index
        int row = flat >> 5, c4 = flat & 31;
        float4 v = *(const float4*)(q_repr + ((long)b * LQ + row) * DIM + c4 * 4);
        float x[4]; *(float4*)x = v;
        ushort4 h, l;
        ushort* hp = (ushort*)&h; ushort* lp = (ushort*)&l;
        #pragma unroll
        for (int j = 0; j < 4; ++j) {
            unsigned int ux = __float_as_uint(x[j]);
            hp[j] = (ushort)(ux >> 16);
            lp[j] = f2b_rn(x[j] - __uint_as_float(ux & 0xffff0000u));
        }
        *(ushort4*)&Qh[row * 136 + c4 * 4] = h;
        *(ushort4*)&Ql[row * 136 + c4 * 4] = l;
    }
    // stage C (64 clusters x 128), rounded bf16
    #pragma unroll
    for (int i = 0; i < 8; ++i) {
        int flat = i * 256 + t;
        int row = flat >> 5, c4 = flat & 31;
        int kk = chunk * 64 + row;
        float4 v = (kk < MAXK)
            ? *(const float4*)(sums + ((long)b * MAXK + kk) * DIM + c4 * 4)
            : make_float4(0.f, 0.f, 0.f, 0.f);
        ushort4 h; ushort* hp = (ushort*)&h;
        hp[0] = f2b_rn(v.x); hp[1] = f2b_rn(v.y);
        hp[2] = f2b_rn(v.z); hp[3] = f2b_rn(v.w);
        *(ushort4*)&Ch[row * 136 + c4 * 4] = h;
    }
    __syncthreads();

    // per-cluster inv-norms from staged C (quad-split over d, shuffle-combine)
    {
        int c = w * 16 + m16;
        float ssv = 0.f;
        #pragma unroll
        for (int j = 0; j < 16; ++j) {
            unsigned int u = *(const unsigned int*)&Ch[c * 136 + quad * 32 + j * 2];
            float x0 = b2f((ushort)u), x1 = b2f((ushort)(u >> 16));
            ssv += x0 * x0 + x1 * x1;
        }
        ssv += __shfl_xor(ssv, 16);
        ssv += __shfl_xor(ssv, 32);
        if (quad == 0) cn[c] = (ssv > 1e-24f) ? rsqrtf(ssv) : 0.f;
    }
    __syncthreads();

    // MFMA: wave w -> q rows [w*16, w*16+16), all 64 clusters (4 ct tiles)
    f32x4 acc[4];
    #pragma unroll
    for (int j = 0; j < 4; ++j) acc[j] = (f32x4){0.f, 0.f, 0.f, 0.f};

    #pragma unroll
    for (int kc = 0; kc < 4; ++kc) {
        short8 qh = *(const short8*)&Qh[(w * 16 + m16) * 136 + kc * 32 + quad * 8];
        short8 ql = *(const short8*)&Ql[(w * 16 + m16) * 136 + kc * 32 + quad * 8];
        #pragma unroll
        for (int ct = 0; ct < 4; ++ct) {
            short8 cf = *(const short8*)&Ch[(ct * 16 + m16) * 136 + kc * 32 + quad * 8];
            acc[ct] = __builtin_amdgcn_mfma_f32_16x16x32_bf16(qh, cf, acc[ct], 0, 0, 0);
            acc[ct] = __builtin_amdgcn_mfma_f32_16x16x32_bf16(ql, cf, acc[ct], 0, 0, 0);
        }
    }

    int kb = kvals[b];
    #pragma unroll
    for (int r = 0; r < 4; ++r) {
        float mx = -1e4f;
        #pragma unroll
        for (int ct = 0; ct < 4; ++ct) {
            int cl = chunk * 64 + ct * 16 + m16;
            float sim = acc[ct][r] * cn[ct * 16 + m16];
            mx = fmaxf(mx, (cl < kb) ? sim : -1e4f);
        }
        mx = fmaxf(mx, __shfl_xor(mx, 1));
        mx = fmaxf(mx, __shfl_xor(mx, 2));
        mx = fmaxf(mx, __shfl_xor(mx, 4));
        mx = fmaxf(mx, __shfl_xor(mx, 8));
        if (m16 == 0)
            pmax[((long)b * SCH + chunk) * 64 + w * 16 + quad * 4 + r] = mx;
    }
}

// ---------------------------------------------------------------------------
// Final: per batch, max over chunks, *q_mask, sum over rows -> out[b]
__global__ __launch_bounds__(64) void final_kernel(
    const float* __restrict__ pmax,
    const int*   __restrict__ q_mask,
    float*       __restrict__ out)
{
    int b = blockIdx.x, r = threadIdx.x;
    float m = -3e38f;
    #pragma unroll
    for (int c = 0; c < SCH; ++c)
        m = fmaxf(m, pmax[((long)b * SCH + c) * 64 + r]);
    m *= (float)q_mask[b * LQ + r];
    #pragma unroll
    for (int sh = 1; sh < 64; sh <<= 1) m += __shfl_xor(m, sh);
    if (r == 0) out[b] = m;
}

// ---------------------------------------------------------------------------
extern "C" void kernel_launch(void* const* d_in, const int* in_sizes, int n_in,
                              void* d_out, int out_size, void* d_ws, size_t ws_size,
                              hipStream_t stream) {
    const float* q_hidden = (const float*)d_in[0];
    const float* d_hidden = (const float*)d_in[1];
    const float* W        = (const float*)d_in[2];
    const float* bias     = (const float*)d_in[3];
    const int*   q_mask   = (const int*)d_in[4];
    const int*   d_mask   = (const int*)d_in[5];
    const int*   labels   = (const int*)d_in[6];
    const int*   pf       = (const int*)d_in[7];

    float* ws     = (float*)d_ws;
    float* q_repr = ws;                                   // 131,072 f
    float* sums   = q_repr + (long)BB * LQ * DIM;         // 1,050,624 f
    float* pmaxb  = sums + (long)BB * MAXK * DIM;         // 16*9*64 = 9,216 f
    int*   kvals  = (int*)(pmaxb + BB * SCH * 64);        // 16
    ushort* Wt    = (ushort*)(kvals + 16);                // 131,072 bf16

    prep_kb_kernel<<<288, 256, 0, stream>>>(W, d_mask, pf, Wt, kvals, sums);
    encode_kernel<<<DGRID + QGRID, 512, 0, stream>>>(d_hidden, q_hidden, Wt, bias,
                                                     d_mask, q_mask, labels, kvals,
                                                     sums, q_repr);
    simmax_kernel<<<BB * SCH, 256, 0, stream>>>(q_repr, sums, kvals, pmaxb);
    final_kernel<<<BB, 64, 0, stream>>>(pmaxb, q_mask, (float*)d_out);
}

// Round 4
// 246.966 us; speedup vs baseline: 1.2030x; 1.0319x over previous
//
#include <hip/hip_runtime.h>
#include <hip/hip_bf16.h>

// Problem constants (from reference)
#define BB    16
#define LQ    64
#define LD    2048
#define HH    1024
#define DIM   128
#define MAXK  513          // LD/PF + 1 with PF=4
#define SCH   9            // ceil(513/64) cluster chunks for simmax
#define NUNITS 2112        // 33792 rows / 16 (2048 d-units + 64 q-units)
#define EGRID 512          // encode blocks (8 wave-slots each = 4096 slots)

typedef __attribute__((ext_vector_type(8))) short short8;
typedef __attribute__((ext_vector_type(4))) float f32x4;

__device__ __forceinline__ float b2f(ushort u) {
    union { float f; unsigned int u32; } c; c.u32 = ((unsigned int)u) << 16; return c.f;
}
__device__ __forceinline__ ushort f2b_rn(float f) {
    unsigned int x = __float_as_uint(f);
    return (ushort)((x + 0x7fffu + ((x >> 16) & 1u)) >> 16);
}

// async global->LDS, 16B/lane; LDS dest = wave-uniform base + lane*16,
// global src is PER-LANE (enables pre-swizzled-source staging).
__device__ __forceinline__ void gld16(void* lds, const void* g) {
    __builtin_amdgcn_global_load_lds(
        (const __attribute__((address_space(1))) unsigned int*)g,
        (__attribute__((address_space(3))) unsigned int*)lds,
        16, 0, 0);
}

// ---------------------------------------------------------------------------
// Fused prep:
//   blocks [0,16):   LDS-tile transpose+round W -> Wt bf16 (coalesced writes)
//   blocks [16,32):  kvals per batch
//   blocks [32,288): zero sums (replaces hipMemsetAsync dispatch)
__global__ __launch_bounds__(256) void prep_kb_kernel(
    const float* __restrict__ W,
    const int*   __restrict__ d_mask,
    const int*   __restrict__ pf,
    ushort*      __restrict__ Wt,
    int*         __restrict__ kvals,
    float*       __restrict__ sums)
{
    int bid = blockIdx.x, t = threadIdx.x;
    if (bid < 16) {
        // transpose 64 h-rows x 128 n-cols per block
        __shared__ ushort tile[128][72];   // stride 72 ushorts = 144B (16B-mult)
        const int h0 = bid * 64;
        #pragma unroll
        for (int i = 0; i < 32; ++i) {     // 64*128/256
            int flat = i * 256 + t;
            int r = flat >> 7, c = flat & 127;
            tile[c][r] = f2b_rn(W[(long)(h0 + r) * DIM + c]);
        }
        __syncthreads();
        #pragma unroll
        for (int i = 0; i < 4; ++i) {      // 128 rows x 8 uint4 = 1024 uint4
            int flat = i * 256 + t;
            int n = flat >> 3, u = flat & 7;
            uint4 v = *(const uint4*)&tile[n][u * 8];
            *(uint4*)&Wt[(long)n * HH + h0 + u * 8] = v;
        }
    } else if (bid < 32) {
        __shared__ int red[4];
        int b = bid - 16;
        int lane = t & 63, wave = t >> 6;
        int s = 0;
        for (int i = t; i < LD; i += 256) s += (d_mask[b * LD + i] > 0) ? 1 : 0;
        #pragma unroll
        for (int m = 1; m < 64; m <<= 1) s += __shfl_xor(s, m);
        if (lane == 0) red[wave] = s;
        __syncthreads();
        if (t == 0) {
            int v = red[0] + red[1] + red[2] + red[3];
            if (v < 2) v = 2;
            int pfv = pf[0];
            if (pfv < 1 || pfv > LD) pfv = 4;   // defensive
            kvals[b] = v / pfv + 1;
        }
    } else {
        // zero sums: BB*MAXK*DIM = 1,050,624 floats = 262,656 float4
        const int total4 = (BB * MAXK * DIM) / 4;
        float4* s4 = (float4*)sums;
        const float4 z = make_float4(0.f, 0.f, 0.f, 0.f);
        for (int i = (bid - 32) * 256 + t; i < total4; i += 256 * 256)
            s4[i] = z;
    }
}

// ---------------------------------------------------------------------------
// Encode, W-stationary: LDS holds one K-quarter of W^T (128 n x 256 k bf16 =
// 64 KB, XOR-swizzled); A streams global->registers (frag layout is per-lane
// contiguous 32B, no LDS round trip). Each wave owns ONE 16-row unit x all
// 128 cols; acc persists across 4 K-phases. Barriers: 2 per phase (8 total)
// vs 64 in the old chunk-locked loop -- between barriers pure per-wave
// dataflow, A prefetch depth 2 in regs hides HBM latency.
// Unit->slot map: 4096 wave-slots (512 blk x 8 waves); even slot s -> unit
// s>>1 (0..2047 = d-units); s%64==1 -> 2048 + s/64 (q-units). ~8.25 active
// waves/CU, balanced, no tail.
// W swizzle: slot (n,u') holds k-unit g = p*32 + (u'^(n&7)); staged via
// pre-swizzled global source (gld16 dest must stay linear); ds_read applies
// the same XOR -> conflict-free (each 4-bank group serves exactly 8 lanes).
// 2 MFMA passes: A split hi+lo (exact), W rounded bf16 (same math as before).
__global__ __launch_bounds__(512, 4) void encode_kernel(
    const float*  __restrict__ Xd,      // [32768][H]
    const float*  __restrict__ Xq,      // [1024][H]
    const ushort* __restrict__ Wt,      // [DIM][H] bf16 rounded
    const float*  __restrict__ bias,    // [DIM]
    const int*    __restrict__ mask_d,  // [32768]
    const int*    __restrict__ mask_q,  // [1024]
    const int*    __restrict__ labels,  // [32768]
    const int*    __restrict__ kvals,   // [BB]
    float*        __restrict__ sums,    // [BB][MAXK][DIM]
    float*        __restrict__ q_repr)  // [1024][DIM]
{
    __shared__ __align__(16) uint4 Wlds[4096];   // 64 KB: [n=128][u'=32] 16B units

    const int t = threadIdx.x;
    const int w = t >> 6, lane = t & 63;
    const int m16 = lane & 15, quad = lane >> 4;
    const int s = blockIdx.x * 8 + w;

    // unit assignment (wave-uniform)
    int unit = -1;
    if ((s & 1) == 0) unit = s >> 1;                    // d-units 0..2047
    else if ((s & 63) == 1) unit = 2048 + (s >> 6);     // q-units 2048..2111
    const bool active = unit >= 0;
    const bool isq = unit >= 2048;

    // A source: lane reads row m16 of its unit at k-offset quad*8 (+c*32)
    long row0 = 0;
    const float* aptr = Xd;   // safe default, loads guarded by `active`
    if (active) {
        row0 = isq ? (long)(unit - 2048) * 16 : (long)unit * 16;
        const float* Xb = isq ? Xq : Xd;
        aptr = Xb + (row0 + m16) * HH + quad * 8;
    }

    f32x4 acc[8];
    #pragma unroll
    for (int j = 0; j < 8; ++j) acc[j] = (f32x4){0.f, 0.f, 0.f, 0.f};

    const int sw8 = m16 & 7;
    const ushort* Wu = (const ushort*)Wlds;

    float4 ast[3][2];   // A prefetch ring, indices compile-time after unroll
    if (active) {
        ast[0][0] = *(const float4*)(aptr);
        ast[0][1] = *(const float4*)(aptr + 4);
        ast[1][0] = *(const float4*)(aptr + 32);
        ast[1][1] = *(const float4*)(aptr + 32 + 4);
    }

    #pragma unroll
    for (int p = 0; p < 4; ++p) {
        __syncthreads();               // everyone done reading W_{p-1}
        // stage W quarter p: wave w fills slots [w*512, w*512+512)
        #pragma unroll
        for (int i = 0; i < 8; ++i) {
            int Si = w * 512 + i * 64 + lane;          // per-lane slot
            int n  = Si >> 5, up = Si & 31;
            const ushort* src = Wt + (long)n * HH + (p * 32 + (up ^ (n & 7))) * 8;
            gld16(&Wlds[w * 512 + i * 64], src);       // uniform LDS base
        }
        __syncthreads();               // implicit vmcnt(0): W_p + A prefetch landed
        if (active) {
            #pragma unroll
            for (int cc = 0; cc < 8; ++cc) {
                const int c = p * 8 + cc;              // global chunk 0..31
                if (c + 2 < 32) {
                    ast[(c + 2) % 3][0] = *(const float4*)(aptr + (c + 2) * 32);
                    ast[(c + 2) % 3][1] = *(const float4*)(aptr + (c + 2) * 32 + 4);
                }
                float av[8];
                *(float4*)(av)     = ast[c % 3][0];
                *(float4*)(av + 4) = ast[c % 3][1];
                short8 ah, al;
                #pragma unroll
                for (int j = 0; j < 8; ++j) {
                    unsigned int ux = __float_as_uint(av[j]);
                    ah[j] = (short)(ux >> 16);
                    float hif = __uint_as_float(ux & 0xffff0000u);
                    al[j] = (short)(__float_as_uint(av[j] - hif) >> 16);
                }
                #pragma unroll
                for (int ct = 0; ct < 8; ++ct) {
                    short8 bf = *(const short8*)
                        &Wu[(ct * 16 + m16) * 256 + ((cc * 4 + quad) ^ sw8) * 8];
                    acc[ct] = __builtin_amdgcn_mfma_f32_16x16x32_bf16(ah, bf, acc[ct], 0, 0, 0);
                    acc[ct] = __builtin_amdgcn_mfma_f32_16x16x32_bf16(al, bf, acc[ct], 0, 0, 0);
                }
            }
        }
    }

    // epilogue: bias, in-wave row norm (full 128 cols per wave), mask, scatter
    if (!active) return;

    float bia[8];
    #pragma unroll
    for (int ct = 0; ct < 8; ++ct) bia[ct] = bias[ct * 16 + m16];

    float vv[8][4];
    float ssp[4] = {0.f, 0.f, 0.f, 0.f};
    #pragma unroll
    for (int ct = 0; ct < 8; ++ct)
        #pragma unroll
        for (int r = 0; r < 4; ++r) {
            vv[ct][r] = acc[ct][r] + bia[ct];
            ssp[r] += vv[ct][r] * vv[ct][r];
        }
    #pragma unroll
    for (int r = 0; r < 4; ++r) {
        ssp[r] += __shfl_xor(ssp[r], 1);
        ssp[r] += __shfl_xor(ssp[r], 2);
        ssp[r] += __shfl_xor(ssp[r], 4);
        ssp[r] += __shfl_xor(ssp[r], 8);
    }

    #pragma unroll
    for (int r = 0; r < 4; ++r) {
        long rowg = row0 + quad * 4 + r;
        float scale = 1.0f / fmaxf(sqrtf(ssp[r]), 1e-12f);
        if (isq) {
            scale *= (float)mask_q[rowg];
            #pragma unroll
            for (int ct = 0; ct < 8; ++ct)
                q_repr[rowg * DIM + ct * 16 + m16] = vv[ct][r] * scale;
        } else if (mask_d[rowg] > 0) {
            int b = (int)(rowg >> 11);
            int seg = labels[rowg] % kvals[b];
            float* sp = sums + ((long)b * MAXK + seg) * DIM + m16;
            #pragma unroll
            for (int ct = 0; ct < 8; ++ct)
                atomicAdd(sp + ct * 16, vv[ct][r] * scale);
        }
    }
}

// ---------------------------------------------------------------------------
// Sim via MFMA: block = (b, 64-cluster chunk). Stage Q (split bf16) and C
// (rounded bf16) in LDS, 16x16x32 MFMA over K=DIM=128, normalize(sum) trick
// via per-cluster rsqrt, shuffle-max over clusters -> pmax[b][chunk][64].
__global__ __launch_bounds__(256) void simmax_kernel(
    const float* __restrict__ q_repr,   // [B][LQ][DIM]
    const float* __restrict__ sums,     // [B][MAXK][DIM] raw cluster sums
    const int*   __restrict__ kvals,
    float*       __restrict__ pmax)     // [B][SCH][64]
{
    __shared__ __align__(16) ushort Qh[64 * 136];
    __shared__ __align__(16) ushort Ql[64 * 136];
    __shared__ __align__(16) ushort Ch[64 * 136];
    __shared__ float cn[64];

    int b = blockIdx.x / SCH, chunk = blockIdx.x % SCH;
    int t = threadIdx.x, w = t >> 6, lane = t & 63;
    int m16 = lane & 15, quad = lane >> 4;

    // stage Q (64 rows x 128), split hi/lo
    #pragma unroll
    for (int i = 0; i < 8; ++i) {
        int flat = i * 256 + t;          // float4 index
        int row = flat >> 5, c4 = flat & 31;
        float4 v = *(const float4*)(q_repr + ((long)b * LQ + row) * DIM + c4 * 4);
        float x[4]; *(float4*)x = v;
        ushort4 h, l;
        ushort* hp = (ushort*)&h; ushort* lp = (ushort*)&l;
        #pragma unroll
        for (int j = 0; j < 4; ++j) {
            unsigned int ux = __float_as_uint(x[j]);
            hp[j] = (ushort)(ux >> 16);
            lp[j] = f2b_rn(x[j] - __uint_as_float(ux & 0xffff0000u));
        }
        *(ushort4*)&Qh[row * 136 + c4 * 4] = h;
        *(ushort4*)&Ql[row * 136 + c4 * 4] = l;
    }
    // stage C (64 clusters x 128), rounded bf16
    #pragma unroll
    for (int i = 0; i < 8; ++i) {
        int flat = i * 256 + t;
        int row = flat >> 5, c4 = flat & 31;
        int kk = chunk * 64 + row;
        float4 v = (kk < MAXK)
            ? *(const float4*)(sums + ((long)b * MAXK + kk) * DIM + c4 * 4)
            : make_float4(0.f, 0.f, 0.f, 0.f);
        ushort4 h; ushort* hp = (ushort*)&h;
        hp[0] = f2b_rn(v.x); hp[1] = f2b_rn(v.y);
        hp[2] = f2b_rn(v.z); hp[3] = f2b_rn(v.w);
        *(ushort4*)&Ch[row * 136 + c4 * 4] = h;
    }
    __syncthreads();

    // per-cluster inv-norms from staged C (quad-split over d, shuffle-combine)
    {
        int c = w * 16 + m16;
        float ssv = 0.f;
        #pragma unroll
        for (int j = 0; j < 16; ++j) {
            unsigned int u = *(const unsigned int*)&Ch[c * 136 + quad * 32 + j * 2];
            float x0 = b2f((ushort)u), x1 = b2f((ushort)(u >> 16));
            ssv += x0 * x0 + x1 * x1;
        }
        ssv += __shfl_xor(ssv, 16);
        ssv += __shfl_xor(ssv, 32);
        if (quad == 0) cn[c] = (ssv > 1e-24f) ? rsqrtf(ssv) : 0.f;
    }
    __syncthreads();

    // MFMA: wave w -> q rows [w*16, w*16+16), all 64 clusters (4 ct tiles)
    f32x4 acc[4];
    #pragma unroll
    for (int j = 0; j < 4; ++j) acc[j] = (f32x4){0.f, 0.f, 0.f, 0.f};

    #pragma unroll
    for (int kc = 0; kc < 4; ++kc) {
        short8 qh = *(const short8*)&Qh[(w * 16 + m16) * 136 + kc * 32 + quad * 8];
        short8 ql = *(const short8*)&Ql[(w * 16 + m16) * 136 + kc * 32 + quad * 8];
        #pragma unroll
        for (int ct = 0; ct < 4; ++ct) {
            short8 cf = *(const short8*)&Ch[(ct * 16 + m16) * 136 + kc * 32 + quad * 8];
            acc[ct] = __builtin_amdgcn_mfma_f32_16x16x32_bf16(qh, cf, acc[ct], 0, 0, 0);
            acc[ct] = __builtin_amdgcn_mfma_f32_16x16x32_bf16(ql, cf, acc[ct], 0, 0, 0);
        }
    }

    int kb = kvals[b];
    #pragma unroll
    for (int r = 0; r < 4; ++r) {
        float mx = -1e4f;
        #pragma unroll
        for (int ct = 0; ct < 4; ++ct) {
            int cl = chunk * 64 + ct * 16 + m16;
            float sim = acc[ct][r] * cn[ct * 16 + m16];
            mx = fmaxf(mx, (cl < kb) ? sim : -1e4f);
        }
        mx = fmaxf(mx, __shfl_xor(mx, 1));
        mx = fmaxf(mx, __shfl_xor(mx, 2));
        mx = fmaxf(mx, __shfl_xor(mx, 4));
        mx = fmaxf(mx, __shfl_xor(mx, 8));
        if (m16 == 0)
            pmax[((long)b * SCH + chunk) * 64 + w * 16 + quad * 4 + r] = mx;
    }
}

// ---------------------------------------------------------------------------
// Final: per batch, max over chunks, *q_mask, sum over rows -> out[b]
__global__ __launch_bounds__(64) void final_kernel(
    const float* __restrict__ pmax,
    const int*   __restrict__ q_mask,
    float*       __restrict__ out)
{
    int b = blockIdx.x, r = threadIdx.x;
    float m = -3e38f;
    #pragma unroll
    for (int c = 0; c < SCH; ++c)
        m = fmaxf(m, pmax[((long)b * SCH + c) * 64 + r]);
    m *= (float)q_mask[b * LQ + r];
    #pragma unroll
    for (int sh = 1; sh < 64; sh <<= 1) m += __shfl_xor(m, sh);
    if (r == 0) out[b] = m;
}

// ---------------------------------------------------------------------------
extern "C" void kernel_launch(void* const* d_in, const int* in_sizes, int n_in,
                              void* d_out, int out_size, void* d_ws, size_t ws_size,
                              hipStream_t stream) {
    const float* q_hidden = (const float*)d_in[0];
    const float* d_hidden = (const float*)d_in[1];
    const float* W        = (const float*)d_in[2];
    const float* bias     = (const float*)d_in[3];
    const int*   q_mask   = (const int*)d_in[4];
    const int*   d_mask   = (const int*)d_in[5];
    const int*   labels   = (const int*)d_in[6];
    const int*   pf       = (const int*)d_in[7];

    float* ws     = (float*)d_ws;
    float* q_repr = ws;                                   // 131,072 f
    float* sums   = q_repr + (long)BB * LQ * DIM;         // 1,050,624 f
    float* pmaxb  = sums + (long)BB * MAXK * DIM;         // 16*9*64 = 9,216 f
    int*   kvals  = (int*)(pmaxb + BB * SCH * 64);        // 16
    ushort* Wt    = (ushort*)(kvals + 16);                // 131,072 bf16

    prep_kb_kernel<<<288, 256, 0, stream>>>(W, d_mask, pf, Wt, kvals, sums);
    encode_kernel<<<EGRID, 512, 0, stream>>>(d_hidden, q_hidden, Wt, bias,
                                             d_mask, q_mask, labels, kvals,
                                             sums, q_repr);
    simmax_kernel<<<BB * SCH, 256, 0, stream>>>(q_repr, sums, kvals, pmaxb);
    final_kernel<<<BB, 64, 0, stream>>>(pmaxb, q_mask, (float*)d_out);
}